// Round 6
// baseline (840.565 us; speedup 1.0000x reference)
//
#include <hip/hip_runtime.h>

// QLSTM: B=512, T=1024, IN=1, H=64.
// R6: M=2 batch-element amortization. Five rounds proved the compiler will
// NOT keep the 64 recurrent weights/lane resident across the t-loop (VGPR
// 44/32 regardless of pins/volatile/waves_per_eu), so every CU re-streams
// its weight working set from L1/L2 each step: 2 blocks x 4 waves x 16 KB =
// 128 KB/step/CU ~= 1000-2300 cyc supply ~= the measured 1355 cyc/step.
// Caches cannot amortize operand requests; registers reused WITHIN a step
// can. Each block now owns TWO batch elements: each weight quad is loaded
// once per step and FMA'd against both elements' h. Weight traffic halves
// (64 KB/step/CU); grid 512/2=256 blocks = 1 block/CU.
//
// Structure (per block): 4 waves, wave w = gate w (i,f,g,o), lane l = unit l.
// Per-element math is BIT-IDENTICAL serial order to the verified 586us
// kernel (absmax 0.0); element 1 is an independent interleaved chain (also
// doubles dot-chain ILP, covering dep latency at 1 wave/SIMD).
//
// Sync structure (1 barrier/step), as verified:
//  - per-wave PRIVATE LDS h copies hs4[w][m][64]: same-wave write->read
//    ordering, no barrier.
//  - gate activations exchanged via DOUBLE-BUFFERED act[t&1][4][m][64]:
//    parity prevents WAR without a second barrier.
//  - c,h update computed redundantly by all 4 waves for both elements.

#define TLEN 1024
#define HID  64

__device__ __forceinline__ float fast_sigmoid(float x) {
    return __builtin_amdgcn_rcpf(1.0f + __expf(-x));   // hw exp + hw rcp
}
__device__ __forceinline__ float fast_tanh(float x) {
    return __builtin_fmaf(2.0f, fast_sigmoid(2.0f * x), -1.0f);
}

__global__ __launch_bounds__(256)
void qlstm_kernel(const float* __restrict__ x,      // [B, T, 1]
                  const float* __restrict__ W_ih,   // [256, 1]
                  const float* __restrict__ W_hh,   // [256, 64]
                  const float* __restrict__ b_ih,   // [256]
                  const float* __restrict__ b_hh,   // [256]
                  const float* __restrict__ W_lin,  // [1, 64]
                  const float* __restrict__ b_lin,  // [1]
                  float* __restrict__ out)          // [B]
{
    const int b0  = blockIdx.x * 2;     // this block's two batch elements
    const int tid = threadIdx.x;
    const int w   = tid >> 6;   // wave id == gate id
    const int l   = tid & 63;   // hidden unit

    __shared__ __align__(16) float xs[2][TLEN];         // 8 KB
    __shared__ __align__(16) float hs4[4][2][HID];      // 2 KB per-wave h copies
    __shared__ __align__(16) float act[2][4][2][HID];   // 4 KB dbuf gate acts

    // Stage both x rows (2048 floats, contiguous since b1=b0+1): 2 float4/thread.
    {
        const float4* src = (const float4*)(x + (size_t)b0 * TLEN);
        float4* dst = (float4*)xs;
        dst[tid]       = src[tid];
        dst[tid + 256] = src[tid + 256];
    }

    const int row = w * HID + l;
    const float4* Wr = (const float4*)(W_hh + (size_t)row * HID);

    const float u    = W_ih[row];                 // IN == 1
    const float bias = b_ih[row] + b_hh[row];
    const float wlin = W_lin[l];

    float c0 = 0.0f, h0 = 0.0f, c1 = 0.0f, h1 = 0.0f;
    hs4[w][0][l] = 0.0f;
    hs4[w][1][l] = 0.0f;
    __syncthreads();   // xs + hs4 ready

    for (int t = 0; t < TLEN; ++t) {
        const int p = t & 1;
        const float xt0 = xs[0][t];               // same-address broadcasts
        const float xt1 = xs[1][t];

        // Two independent dot chains; each weight quad loaded ONCE, used for
        // both elements (the amortization). Per-element FMA order identical
        // to the verified kernel.
        float acc0 = __builtin_fmaf(xt0, u, bias);
        float acc1 = __builtin_fmaf(xt1, u, bias);
        #pragma unroll
        for (int q = 0; q < 16; ++q) {
            const float4 wv  = Wr[q];                              // 1 load, 2 uses
            const float4 hk0 = *(const float4*)&hs4[w][0][4 * q];  // b128 bcast
            const float4 hk1 = *(const float4*)&hs4[w][1][4 * q];
            acc0 = __builtin_fmaf(hk0.x, wv.x, acc0);
            acc1 = __builtin_fmaf(hk1.x, wv.x, acc1);
            acc0 = __builtin_fmaf(hk0.y, wv.y, acc0);
            acc1 = __builtin_fmaf(hk1.y, wv.y, acc1);
            acc0 = __builtin_fmaf(hk0.z, wv.z, acc0);
            acc1 = __builtin_fmaf(hk1.z, wv.z, acc1);
            acc0 = __builtin_fmaf(hk0.w, wv.w, acc0);
            acc1 = __builtin_fmaf(hk1.w, wv.w, acc1);
        }

        // This wave's activations (wave-uniform branch).
        const float a0 = (w == 2) ? fast_tanh(acc0) : fast_sigmoid(acc0);
        const float a1 = (w == 2) ? fast_tanh(acc1) : fast_sigmoid(acc1);
        act[p][w][0][l] = a0;                     // stride-1, conflict-free
        act[p][w][1][l] = a1;
        __syncthreads();                          // the ONE barrier per step

        // Redundant elementwise update in every wave, both elements.
        {
            const float ai = act[p][0][0][l];
            const float af = act[p][1][0][l];
            const float ag = act[p][2][0][l];
            const float ao = act[p][3][0][l];
            c0 = __builtin_fmaf(af, c0, ai * ag);
            h0 = ao * fast_tanh(c0);
            hs4[w][0][l] = h0;                    // private copy; no barrier
        }
        {
            const float ai = act[p][0][1][l];
            const float af = act[p][1][1][l];
            const float ag = act[p][2][1][l];
            const float ao = act[p][3][1][l];
            c1 = __builtin_fmaf(af, c1, ai * ag);
            h1 = ao * fast_tanh(c1);
            hs4[w][1][l] = h1;                    // private copy; no barrier
        }
    }

    // out[b0+m] = dot(h_m, W_lin) + b_lin : wave 0 -> m=0, wave 1 -> m=1.
    if (w == 0 || w == 1) {
        float v = ((w == 0) ? h0 : h1) * wlin;
        #pragma unroll
        for (int off = 32; off > 0; off >>= 1)
            v += __shfl_down(v, off, 64);
        if (l == 0) out[b0 + w] = v + b_lin[0];
    }
}

extern "C" void kernel_launch(void* const* d_in, const int* in_sizes, int n_in,
                              void* d_out, int out_size, void* d_ws, size_t ws_size,
                              hipStream_t stream) {
    const float* x     = (const float*)d_in[0];
    const float* W_ih  = (const float*)d_in[1];
    const float* W_hh  = (const float*)d_in[2];
    const float* b_ih  = (const float*)d_in[3];
    const float* b_hh  = (const float*)d_in[4];
    const float* W_lin = (const float*)d_in[5];
    const float* b_lin = (const float*)d_in[6];
    float* out = (float*)d_out;

    const int B = out_size;  // 512
    qlstm_kernel<<<B / 2, 256, 0, stream>>>(x, W_ih, W_hh, b_ih, b_hh, W_lin, b_lin, out);
}